// Round 10
// baseline (1252.648 us; speedup 1.0000x reference)
//
#include <hip/hip_runtime.h>

#define CC 100000
#define DD 512

#define S_SCALE 30.0f
#define COS_M_C 0.8775825618903728f
#define SIN_M_C 0.479425538604203f
#define THRESH_C (-0.8775825618903728f)
#define MM_C 0.2397127693021015f

typedef __attribute__((ext_vector_type(8))) short short8;
typedef __attribute__((ext_vector_type(4))) float f32x4;

static __device__ __forceinline__ unsigned short f2bf(float x) {
  unsigned int u = __float_as_uint(x);
  unsigned int r = (u + 0x7fffu + ((u >> 16) & 1u)) >> 16;
  return (unsigned short)r;
}

#define FENCE() __builtin_amdgcn_sched_barrier(0)

// ---------------------------------------------------------------------------
// Kernel 1: per embedding row i: normalize, bf16, store to wsA in MFMA
// FRAGMENT order (validated r8/r9):
//   byte addr = (k>>5)*32768 + (i>>6)*4096 + ((i>>4)&3)*1024
//             + (((k>>3)&3)*16 + (i&15))*16
// ---------------------------------------------------------------------------
__global__ __launch_bounds__(64) void k1_prep(
    const float* __restrict__ emb, const float* __restrict__ kern,
    const int* __restrict__ label, unsigned short* __restrict__ wsA,
    float* __restrict__ ws_target, float* __restrict__ ws_ctm,
    float* __restrict__ ws_ft) {
  const int i = blockIdx.x;
  const int l = threadIdx.x;

  const float4* er = reinterpret_cast<const float4*>(emb + (size_t)i * DD + l * 8);
  float4 v0 = er[0], v1 = er[1];
  float e[8] = {v0.x, v0.y, v0.z, v0.w, v1.x, v1.y, v1.z, v1.w};

  float esq = 0.f;
#pragma unroll
  for (int j = 0; j < 8; ++j) esq += e[j] * e[j];
#pragma unroll
  for (int o = 32; o > 0; o >>= 1) esq += __shfl_xor(esq, o);
  const float inv = rsqrtf(esq);

  const int c = label[i];
  float dot = 0.f, wsq = 0.f;
#pragma unroll
  for (int j = 0; j < 8; ++j) {
    float w = kern[(size_t)(l * 8 + j) * CC + c];
    dot += e[j] * w;
    wsq += w * w;
  }
#pragma unroll
  for (int o = 32; o > 0; o >>= 1) {
    dot += __shfl_xor(dot, o);
    wsq += __shfl_xor(wsq, o);
  }

  unsigned int pk[4];
#pragma unroll
  for (int j = 0; j < 4; ++j) {
    unsigned int lo = f2bf(e[2 * j] * inv);
    unsigned int hi = f2bf(e[2 * j + 1] * inv);
    pk[j] = lo | (hi << 16);
  }
  const int off = (l >> 2) * 32768 + (i >> 6) * 4096 + (((i >> 4) & 3)) * 1024 +
                  ((l & 3) * 16 + (i & 15)) * 16;
  uint4 v; v.x = pk[0]; v.y = pk[1]; v.z = pk[2]; v.w = pk[3];
  *reinterpret_cast<uint4*>(reinterpret_cast<char*>(wsA) + off) = v;

  if (l == 0) {
    float t = dot * rsqrtf(fmaxf(esq * wsq, 1e-30f));
    t = fminf(fmaxf(t, -1.f), 1.f);
    float st = sqrtf(fmaxf(0.f, 1.f - t * t));
    float ctm = t * COS_M_C - st * SIN_M_C;
    ws_target[i] = t;
    ws_ctm[i] = ctm;
    ws_ft[i] = (t > THRESH_C) ? ctm : (t - MM_C);
  }
}

// ---------------------------------------------------------------------------
// Kernel 2: deterministic reduction of 512 target logits -> t_new
// ---------------------------------------------------------------------------
__global__ __launch_bounds__(64) void k2_tnew(const float* __restrict__ ws_target,
                                              const float* __restrict__ t_in,
                                              float* __restrict__ ws_tnew) {
  const int l = threadIdx.x;
  float s = 0.f;
#pragma unroll
  for (int j = 0; j < 8; ++j) s += ws_target[l * 8 + j];
#pragma unroll
  for (int o = 32; o > 0; o >>= 1) s += __shfl_xor(s, o);
  if (l == 0) ws_tnew[0] = 0.01f * (s * (1.0f / 512.0f)) + 0.99f * t_in[0];
}

// ---------------------------------------------------------------------------
// Kernel 3: 512x64 GEMM + epilogue. LDS diet -> 4 blocks/CU:
//  - A: direct global->VGPR fragment loads (wsA fragment order, L2-hot),
//    issued at iter top for ~full-iter cover. No A LDS.
//  - B: r6's validated LDS double-buffer (2x4KB) + 1-iter reg prefetch,
//    ONE barrier per iter. Queue invariant at iter entry: [B(kt+1):4].
//  - Epilogue scratch 8.7KB (4-row phases). Total LDS ~17.2KB.
//  - __launch_bounds__(512,8): 256-reg budget, ~116 used, no spill.
// ---------------------------------------------------------------------------
__global__ __launch_bounds__(512, 8) void k3_gemm(
    const float* __restrict__ kern, const unsigned short* __restrict__ wsA,
    const int* __restrict__ label, const float* __restrict__ ws_ctm,
    const float* __restrict__ ws_ft, const float* __restrict__ ws_tnew,
    float* __restrict__ out) {
  __shared__ __align__(16) char smem[8192 + 8704];  // B 2x4KB + est 8x1088B
  __shared__ float colsq[64];

  const int t = threadIdx.x;
  const int l = t & 63;
  const int wv = t >> 6;
  const int lr = l & 15;
  const int lg = l >> 4;
  const int n0 = blockIdx.x * 64;

  if (t < 64) colsq[t] = 0.f;

  const int bn = l;
  const int gcol = n0 + bn;
  const bool colok = gcol < CC;
  const float* bcol = kern + gcol;

  float sumsq = 0.f;

  f32x4 acc[4][4];
#pragma unroll
  for (int a = 0; a < 4; ++a)
#pragma unroll
    for (int b = 0; b < 4; ++b) acc[a][b] = (f32x4){0.f, 0.f, 0.f, 0.f};

  char* Bb = smem;
  const char* pA = reinterpret_cast<const char*>(wsA) + wv * 4096 + l * 16;
  // B read swizzle (r6-validated): chunk = lg ^ (lr&3) ^ ((lr>>2)&3)
  const int swz = ((lg ^ (lr & 3) ^ ((lr >> 2) & 3)) << 4);

#define BLOAD(KT, r0, r1, r2, r3)                                        \
  {                                                                      \
    if (colok) {                                                         \
      const float* p_ = bcol + (size_t)((KT) * 32 + wv * 4) * CC;        \
      r0 = p_[0];                                                        \
      r1 = p_[(size_t)CC];                                               \
      r2 = p_[(size_t)2 * CC];                                           \
      r3 = p_[(size_t)3 * CC];                                           \
    } else {                                                             \
      r0 = r1 = r2 = r3 = 0.f;                                           \
    }                                                                    \
  }

#define BWRITE(KT, r0, r1, r2, r3)                                       \
  {                                                                      \
    sumsq += r0 * r0 + r1 * r1 + r2 * r2 + r3 * r3;                      \
    uint2 pk_;                                                           \
    pk_.x = (unsigned int)f2bf(r0) | ((unsigned int)f2bf(r1) << 16);     \
    pk_.y = (unsigned int)f2bf(r2) | ((unsigned int)f2bf(r3) << 16);     \
    const int wb_ = bn * 64 +                                            \
                    ((((wv >> 1) ^ (bn & 3) ^ ((bn >> 2) & 3)) << 4) |   \
                     ((wv & 1) << 3));                                   \
    *reinterpret_cast<uint2*>(Bb + ((KT)&1) * 4096 + wb_) = pk_;         \
  }

  // ---- prologue ----
  float c0, c1, c2, c3;  // B(0)
  float p0, p1, p2, p3;  // B(kt+1), loop-carried
  BLOAD(0, c0, c1, c2, c3);
  FENCE();
  BLOAD(1, p0, p1, p2, p3);
  FENCE();
  // queue: [B0:4, B1:4]
  asm volatile("s_waitcnt vmcnt(4)" ::: "memory");  // B0 landed
  BWRITE(0, c0, c1, c2, c3);
  asm volatile("s_waitcnt lgkmcnt(0)" ::: "memory");
  FENCE();
  __builtin_amdgcn_s_barrier();
  FENCE();
  // enter loop: queue = [B1:4]

  for (int kt = 0; kt < 16; ++kt) {
    const int cur = kt & 1;
    // 1. issue A fragment loads (direct from global, L2-hot)
    short8 af[4];
#pragma unroll
    for (int mf = 0; mf < 4; ++mf)
      af[mf] = *reinterpret_cast<const short8*>(pA + kt * 32768 + mf * 1024);
    FENCE();
    // 2-4. retire B(kt+1) regs (iter-old), commit to idle buf, issue B(kt+2)
    if (kt < 15) {
      asm volatile("s_waitcnt vmcnt(4)" ::: "memory");
      BWRITE(kt + 1, p0, p1, p2, p3);
    }
    if (kt < 14) {
      BLOAD(kt + 2, p0, p1, p2, p3);
    }
    FENCE();
    // 5. B fragment ds_reads from current buffer
    short8 bfr[4];
#pragma unroll
    for (int nf = 0; nf < 4; ++nf) {
      const int n = nf * 16 + lr;
      bfr[nf] = *reinterpret_cast<const short8*>(Bb + cur * 4096 + n * 64 + swz);
    }
    // 6. af landed (B(kt+2) stays in flight across the barrier); ds done
    if (kt < 14) {
      asm volatile("s_waitcnt vmcnt(4)" ::: "memory");
    } else {
      asm volatile("s_waitcnt vmcnt(0)" ::: "memory");
    }
    asm volatile("s_waitcnt lgkmcnt(0)" ::: "memory");
    FENCE();
    // 7. MFMA
    __builtin_amdgcn_s_setprio(1);
#pragma unroll
    for (int mf = 0; mf < 4; ++mf)
#pragma unroll
      for (int nf = 0; nf < 4; ++nf)
        acc[mf][nf] = __builtin_amdgcn_mfma_f32_16x16x32_bf16(
            af[mf], bfr[nf], acc[mf][nf], 0, 0, 0);
    __builtin_amdgcn_s_setprio(0);
    FENCE();
    // 8. single barrier: my BWRITE is drained (lgkm0 above); all waves'
    //    reads of buf[cur] retired before they arrive here.
    __builtin_amdgcn_s_barrier();
    FENCE();
  }

  // ---- column-norm reduce ----
  atomicAdd(&colsq[bn], sumsq);
  asm volatile("s_waitcnt lgkmcnt(0)" ::: "memory");
  FENCE();
  __builtin_amdgcn_s_barrier();
  FENCE();

  const float tnew = ws_tnew[0];
  float invn[4];
#pragma unroll
  for (int nf = 0; nf < 4; ++nf)
    invn[nf] = rsqrtf(fmaxf(colsq[nf * 16 + lr], 1e-30f));

  // ---- epilogue: 4-row phased transpose through wave-private LDS ----
  // phase p of mf: rows p*4..p*4+3 (only lg==p lanes produce them),
  // then every lane stores float4 of row p*4+lg at cols lr*4.
  float* est = reinterpret_cast<float*>(smem + 8192) + (size_t)wv * 272;  // 4x68
  const int c4 = n0 + lr * 4;
#pragma unroll
  for (int mf = 0; mf < 4; ++mf) {
#pragma unroll
    for (int p = 0; p < 4; ++p) {
      asm volatile("s_waitcnt lgkmcnt(0)" ::: "memory");  // WAR vs prev phase
      FENCE();
      if (lg == p) {
#pragma unroll
        for (int r = 0; r < 4; ++r)
#pragma unroll
          for (int nf = 0; nf < 4; ++nf)
            est[r * 68 + nf * 16 + lr] = acc[mf][nf][r] * invn[nf];
      }
      asm volatile("s_waitcnt lgkmcnt(0)" ::: "memory");  // RAW
      FENCE();
      const int m = wv * 64 + mf * 16 + p * 4 + lg;
      const float ctm = ws_ctm[m];
      const float ft = ws_ft[m];
      const int lab = label[m];
      float4 vv = *reinterpret_cast<const float4*>(&est[lg * 68 + lr * 4]);
      if (c4 < CC) {
        float ov[4] = {vv.x, vv.y, vv.z, vv.w};
#pragma unroll
        for (int j = 0; j < 4; ++j) {
          float cosv = fminf(fmaxf(ov[j], -1.f), 1.f);
          float val = (cosv > ctm) ? cosv * (tnew + cosv) : cosv;
          if (c4 + j == lab) val = ft;
          ov[j] = val * S_SCALE;
        }
        float4 st4;
        st4.x = ov[0]; st4.y = ov[1]; st4.z = ov[2]; st4.w = ov[3];
        *reinterpret_cast<float4*>(out + (size_t)m * CC + c4) = st4;
      }
    }
  }
#undef BLOAD
#undef BWRITE
}

// ---------------------------------------------------------------------------
extern "C" void kernel_launch(void* const* d_in, const int* in_sizes, int n_in,
                              void* d_out, int out_size, void* d_ws,
                              size_t ws_size, hipStream_t stream) {
  (void)in_sizes; (void)n_in; (void)out_size; (void)ws_size;
  const float* emb = (const float*)d_in[0];
  const float* kern = (const float*)d_in[1];
  const int* label = (const int*)d_in[2];
  const float* t_in = (const float*)d_in[3];
  float* out = (float*)d_out;

  char* ws = (char*)d_ws;
  unsigned short* wsA = (unsigned short*)ws;
  float* ws_target = (float*)(ws + 524288);
  float* ws_ctm = (float*)(ws + 526336);
  float* ws_ft = (float*)(ws + 528384);
  float* ws_tnew = (float*)(ws + 530432);

  k1_prep<<<512, 64, 0, stream>>>(emb, kern, label, wsA, ws_target, ws_ctm, ws_ft);
  k2_tnew<<<1, 64, 0, stream>>>(ws_target, t_in, ws_tnew);
  k3_gemm<<<(CC + 63) / 64, 512, 0, stream>>>(kern, wsA, label, ws_ctm, ws_ft,
                                              ws_tnew, out);
}

// Round 12
// 159.135 us; speedup vs baseline: 7.8716x; 7.8716x over previous
//
#include <hip/hip_runtime.h>

#define CC 100000
#define DD 512

#define S_SCALE 30.0f
#define COS_M_C 0.8775825618903728f
#define SIN_M_C 0.479425538604203f
#define THRESH_C (-0.8775825618903728f)
#define MM_C 0.2397127693021015f

typedef __attribute__((ext_vector_type(8))) short short8;
typedef __attribute__((ext_vector_type(4))) float f32x4;

static __device__ __forceinline__ unsigned short f2bf(float x) {
  unsigned int u = __float_as_uint(x);
  unsigned int r = (u + 0x7fffu + ((u >> 16) & 1u)) >> 16;
  return (unsigned short)r;
}

#define FENCE() __builtin_amdgcn_sched_barrier(0)

// ---------------------------------------------------------------------------
// Kernel 1: per embedding row i: normalize, bf16, store to wsA in MFMA
// FRAGMENT order (validated r8-r10):
//   byte addr = (k>>5)*32768 + (i>>6)*4096 + ((i>>4)&3)*1024
//             + (((k>>3)&3)*16 + (i&15))*16
// ---------------------------------------------------------------------------
__global__ __launch_bounds__(64) void k1_prep(
    const float* __restrict__ emb, const float* __restrict__ kern,
    const int* __restrict__ label, unsigned short* __restrict__ wsA,
    float* __restrict__ ws_target, float* __restrict__ ws_ctm,
    float* __restrict__ ws_ft) {
  const int i = blockIdx.x;
  const int l = threadIdx.x;

  const float4* er = reinterpret_cast<const float4*>(emb + (size_t)i * DD + l * 8);
  float4 v0 = er[0], v1 = er[1];
  float e[8] = {v0.x, v0.y, v0.z, v0.w, v1.x, v1.y, v1.z, v1.w};

  float esq = 0.f;
#pragma unroll
  for (int j = 0; j < 8; ++j) esq += e[j] * e[j];
#pragma unroll
  for (int o = 32; o > 0; o >>= 1) esq += __shfl_xor(esq, o);
  const float inv = rsqrtf(esq);

  const int c = label[i];
  float dot = 0.f, wsq = 0.f;
#pragma unroll
  for (int j = 0; j < 8; ++j) {
    float w = kern[(size_t)(l * 8 + j) * CC + c];
    dot += e[j] * w;
    wsq += w * w;
  }
#pragma unroll
  for (int o = 32; o > 0; o >>= 1) {
    dot += __shfl_xor(dot, o);
    wsq += __shfl_xor(wsq, o);
  }

  unsigned int pk[4];
#pragma unroll
  for (int j = 0; j < 4; ++j) {
    unsigned int lo = f2bf(e[2 * j] * inv);
    unsigned int hi = f2bf(e[2 * j + 1] * inv);
    pk[j] = lo | (hi << 16);
  }
  const int off = (l >> 2) * 32768 + (i >> 6) * 4096 + (((i >> 4) & 3)) * 1024 +
                  ((l & 3) * 16 + (i & 15)) * 16;
  uint4 v; v.x = pk[0]; v.y = pk[1]; v.z = pk[2]; v.w = pk[3];
  *reinterpret_cast<uint4*>(reinterpret_cast<char*>(wsA) + off) = v;

  if (l == 0) {
    float t = dot * rsqrtf(fmaxf(esq * wsq, 1e-30f));
    t = fminf(fmaxf(t, -1.f), 1.f);
    float st = sqrtf(fmaxf(0.f, 1.f - t * t));
    float ctm = t * COS_M_C - st * SIN_M_C;
    ws_target[i] = t;
    ws_ctm[i] = ctm;
    ws_ft[i] = (t > THRESH_C) ? ctm : (t - MM_C);
  }
}

// ---------------------------------------------------------------------------
// Kernel 2: deterministic reduction of 512 target logits -> t_new
// ---------------------------------------------------------------------------
__global__ __launch_bounds__(64) void k2_tnew(const float* __restrict__ ws_target,
                                              const float* __restrict__ t_in,
                                              float* __restrict__ ws_tnew) {
  const int l = threadIdx.x;
  float s = 0.f;
#pragma unroll
  for (int j = 0; j < 8; ++j) s += ws_target[l * 8 + j];
#pragma unroll
  for (int o = 32; o > 0; o >>= 1) s += __shfl_xor(s, o);
  if (l == 0) ws_tnew[0] = 0.01f * (s * (1.0f / 512.0f)) + 0.99f * t_in[0];
}

// ---------------------------------------------------------------------------
// Kernel 3: 256x64 tile GEMM + epilogue, FOUR-WAVE independent blocks.
// 16 waves/CU (the hard register cap: 64 AGPR acc + ~50 VGPR = 128/wave)
// now come from 4 INDEPENDENT blocks per CU instead of 2 barrier-coupled
// ones: each SIMD hosts 4 waves of 4 different blocks -> barrier stalls in
// one block are covered by the other three.
//  - A: direct global->VGPR fragment loads from fragment-order wsA
//    (L2-hot). Wave wv of mt-half handles rows (mt*4+wv)*64..+63.
//  - B: LDS double-buffer 2x4KB, one barrier/iter, wave wv supplies
//    k-slice wv (k = kt*32 + 8wv..+7) of each column as ONE b128 write.
//  - blockIdx = nt*2 + mt keeps both readers of each kern column
//    co-resident (L2/L3 locality).
// Steady-state queue at iter entry: [B(kt+1):8].
//   issue af:4 -> vmcnt(4) retires B regs -> BWRITE(kt+1) -> BLOAD(kt+2):8
//   -> ds_reads -> vmcnt(8) retires af (B(kt+2) flies over the barrier)
//   -> lgkm0 -> MFMA -> barrier.  Tails: kt=14 vmcnt(0); kt=15 bare.
// ---------------------------------------------------------------------------
__global__ __launch_bounds__(256, 4) void k3_gemm(
    const float* __restrict__ kern, const unsigned short* __restrict__ wsA,
    const int* __restrict__ label, const float* __restrict__ ws_ctm,
    const float* __restrict__ ws_ft, const float* __restrict__ ws_tnew,
    float* __restrict__ out) {
  __shared__ __align__(16) char smem[8192 + 4352];  // B 2x4KB + est 4x1088B
  __shared__ float colsq[64];

  const int t = threadIdx.x;
  const int l = t & 63;
  const int wv = t >> 6;  // 0..3
  const int lr = l & 15;
  const int lg = l >> 4;
  const int nt = blockIdx.x >> 1;
  const int mt = blockIdx.x & 1;
  const int n0 = nt * 64;
  const int bm0 = mt * 256;

  if (t < 64) colsq[t] = 0.f;

  const int bn = l;
  const int gcol = n0 + bn;
  const bool colok = gcol < CC;
  const float* bcol = kern + gcol;

  float sumsq = 0.f;

  f32x4 acc[4][4];
#pragma unroll
  for (int a = 0; a < 4; ++a)
#pragma unroll
    for (int b = 0; b < 4; ++b) acc[a][b] = (f32x4){0.f, 0.f, 0.f, 0.f};

  char* Bb = smem;
  const char* pA =
      reinterpret_cast<const char*>(wsA) + (mt * 4 + wv) * 4096 + l * 16;
  // read swizzle: k-slice lg of row n -> chunk = lg ^ (n&3) ^ ((n>>2)&3)
  const int swz = ((lg ^ (lr & 3) ^ ((lr >> 2) & 3)) << 4);
  // write: wave wv supplies k-slice wv of its column bn
  const int wb = bn * 64 + (((wv ^ (bn & 3) ^ ((bn >> 2) & 3))) << 4);

#define BLOAD8(KT, r0, r1, r2, r3, r4, r5, r6, r7)                       \
  {                                                                      \
    if (colok) {                                                         \
      const float* q_ = bcol + (size_t)((KT) * 32 + wv * 8) * CC;        \
      r0 = q_[0];              r1 = q_[(size_t)CC];                      \
      r2 = q_[(size_t)2 * CC]; r3 = q_[(size_t)3 * CC];                  \
      r4 = q_[(size_t)4 * CC]; r5 = q_[(size_t)5 * CC];                  \
      r6 = q_[(size_t)6 * CC]; r7 = q_[(size_t)7 * CC];                  \
    } else {                                                             \
      r0 = r1 = r2 = r3 = r4 = r5 = r6 = r7 = 0.f;                       \
    }                                                                    \
  }

#define BWRITE8(KT, r0, r1, r2, r3, r4, r5, r6, r7)                      \
  {                                                                      \
    sumsq += r0 * r0 + r1 * r1 + r2 * r2 + r3 * r3 + r4 * r4 + r5 * r5 + \
             r6 * r6 + r7 * r7;                                          \
    uint4 pk_;                                                           \
    pk_.x = (unsigned int)f2bf(r0) | ((unsigned int)f2bf(r1) << 16);     \
    pk_.y = (unsigned int)f2bf(r2) | ((unsigned int)f2bf(r3) << 16);     \
    pk_.z = (unsigned int)f2bf(r4) | ((unsigned int)f2bf(r5) << 16);     \
    pk_.w = (unsigned int)f2bf(r6) | ((unsigned int)f2bf(r7) << 16);     \
    *reinterpret_cast<uint4*>(Bb + ((KT)&1) * 4096 + wb) = pk_;          \
  }

  // ---- prologue ----
  float q0, q1, q2, q3, q4, q5, q6, q7;  // B(0)
  float p0, p1, p2, p3, p4, p5, p6, p7;  // B(kt+1), loop-carried
  BLOAD8(0, q0, q1, q2, q3, q4, q5, q6, q7);
  FENCE();
  BLOAD8(1, p0, p1, p2, p3, p4, p5, p6, p7);
  FENCE();
  // queue: [B0:8, B1:8]
  asm volatile("s_waitcnt vmcnt(8)" ::: "memory");  // B0 landed
  BWRITE8(0, q0, q1, q2, q3, q4, q5, q6, q7);
  asm volatile("s_waitcnt lgkmcnt(0)" ::: "memory");
  FENCE();
  __builtin_amdgcn_s_barrier();
  FENCE();
  // enter loop: queue = [B1:8]

  for (int kt = 0; kt < 16; ++kt) {
    const int cur = kt & 1;
    // 1. issue A fragment loads (direct from global, L2-hot)
    short8 af[4];
#pragma unroll
    for (int mf = 0; mf < 4; ++mf)
      af[mf] = *reinterpret_cast<const short8*>(pA + kt * 32768 + mf * 1024);
    FENCE();
    // 2-4. retire B(kt+1) regs (iter-old), commit to idle buf, issue B(kt+2)
    if (kt < 15) {
      asm volatile("s_waitcnt vmcnt(4)" ::: "memory");
      BWRITE8(kt + 1, p0, p1, p2, p3, p4, p5, p6, p7);
    }
    if (kt < 14) {
      BLOAD8(kt + 2, p0, p1, p2, p3, p4, p5, p6, p7);
    }
    FENCE();
    // 5. B fragment ds_reads from current buffer
    short8 bfr[4];
#pragma unroll
    for (int nf = 0; nf < 4; ++nf) {
      const int n = nf * 16 + lr;
      bfr[nf] = *reinterpret_cast<const short8*>(Bb + cur * 4096 + n * 64 + swz);
    }
    // 6. af landed (B(kt+2) stays in flight across the barrier); ds done
    if (kt < 14) {
      asm volatile("s_waitcnt vmcnt(8)" ::: "memory");
    } else {
      asm volatile("s_waitcnt vmcnt(0)" ::: "memory");
    }
    asm volatile("s_waitcnt lgkmcnt(0)" ::: "memory");
    FENCE();
    // 7. MFMA
    __builtin_amdgcn_s_setprio(1);
#pragma unroll
    for (int mf = 0; mf < 4; ++mf)
#pragma unroll
      for (int nf = 0; nf < 4; ++nf)
        acc[mf][nf] = __builtin_amdgcn_mfma_f32_16x16x32_bf16(
            af[mf], bfr[nf], acc[mf][nf], 0, 0, 0);
    __builtin_amdgcn_s_setprio(0);
    FENCE();
    // 8. single barrier (4 waves only)
    __builtin_amdgcn_s_barrier();
    FENCE();
  }

  // ---- column-norm reduce (4 waves, disjoint k-slices) ----
  atomicAdd(&colsq[bn], sumsq);
  asm volatile("s_waitcnt lgkmcnt(0)" ::: "memory");
  FENCE();
  __builtin_amdgcn_s_barrier();
  FENCE();

  const float tnew = ws_tnew[0];
  float invn[4];
#pragma unroll
  for (int nf = 0; nf < 4; ++nf)
    invn[nf] = rsqrtf(fmaxf(colsq[nf * 16 + lr], 1e-30f));

  // ---- epilogue: 4-row phased transpose through wave-private LDS ----
  float* est = reinterpret_cast<float*>(smem + 8192) + (size_t)wv * 272;  // 4x68
  const int c4 = n0 + lr * 4;
#pragma unroll
  for (int mf = 0; mf < 4; ++mf) {
#pragma unroll
    for (int p = 0; p < 4; ++p) {
      asm volatile("s_waitcnt lgkmcnt(0)" ::: "memory");  // WAR vs prev phase
      FENCE();
      if (lg == p) {
#pragma unroll
        for (int r = 0; r < 4; ++r)
#pragma unroll
          for (int nf = 0; nf < 4; ++nf)
            est[r * 68 + nf * 16 + lr] = acc[mf][nf][r] * invn[nf];
      }
      asm volatile("s_waitcnt lgkmcnt(0)" ::: "memory");  // RAW
      FENCE();
      const int m = bm0 + wv * 64 + mf * 16 + p * 4 + lg;
      const float ctm = ws_ctm[m];
      const float ft = ws_ft[m];
      const int lab = label[m];
      float4 vv = *reinterpret_cast<const float4*>(&est[lg * 68 + lr * 4]);
      if (c4 < CC) {
        float ov[4] = {vv.x, vv.y, vv.z, vv.w};
#pragma unroll
        for (int j = 0; j < 4; ++j) {
          float cosv = fminf(fmaxf(ov[j], -1.f), 1.f);
          float val = (cosv > ctm) ? cosv * (tnew + cosv) : cosv;
          if (c4 + j == lab) val = ft;
          ov[j] = val * S_SCALE;
        }
        float4 st4;
        st4.x = ov[0]; st4.y = ov[1]; st4.z = ov[2]; st4.w = ov[3];
        *reinterpret_cast<float4*>(out + (size_t)m * CC + c4) = st4;
      }
    }
  }
#undef BLOAD8
#undef BWRITE8
}

// ---------------------------------------------------------------------------
extern "C" void kernel_launch(void* const* d_in, const int* in_sizes, int n_in,
                              void* d_out, int out_size, void* d_ws,
                              size_t ws_size, hipStream_t stream) {
  (void)in_sizes; (void)n_in; (void)out_size; (void)ws_size;
  const float* emb = (const float*)d_in[0];
  const float* kern = (const float*)d_in[1];
  const int* label = (const int*)d_in[2];
  const float* t_in = (const float*)d_in[3];
  float* out = (float*)d_out;

  char* ws = (char*)d_ws;
  unsigned short* wsA = (unsigned short*)ws;
  float* ws_target = (float*)(ws + 524288);
  float* ws_ctm = (float*)(ws + 526336);
  float* ws_ft = (float*)(ws + 528384);
  float* ws_tnew = (float*)(ws + 530432);

  k1_prep<<<512, 64, 0, stream>>>(emb, kern, label, wsA, ws_target, ws_ctm, ws_ft);
  k2_tnew<<<1, 64, 0, stream>>>(ws_target, t_in, ws_tnew);
  const int ntiles = (CC + 63) / 64;  // 1563
  k3_gemm<<<ntiles * 2, 256, 0, stream>>>(kern, wsA, label, ws_ctm, ws_ft,
                                          ws_tnew, out);
}

// Round 13
// 153.449 us; speedup vs baseline: 8.1633x; 1.0371x over previous
//
#include <hip/hip_runtime.h>

#define CC 100000
#define DD 512
#define NT_TILES 782  // ceil(100000/128)

#define S_SCALE 30.0f
#define COS_M_C 0.8775825618903728f
#define SIN_M_C 0.479425538604203f
#define THRESH_C (-0.8775825618903728f)
#define MM_C 0.2397127693021015f

typedef __attribute__((ext_vector_type(8))) short short8;
typedef __attribute__((ext_vector_type(4))) float f32x4;

static __device__ __forceinline__ unsigned short f2bf(float x) {
  unsigned int u = __float_as_uint(x);
  unsigned int r = (u + 0x7fffu + ((u >> 16) & 1u)) >> 16;
  return (unsigned short)r;
}

#define FENCE() __builtin_amdgcn_sched_barrier(0)

// ---------------------------------------------------------------------------
// Kernel 1: per embedding row i: normalize, bf16, store to wsA in MFMA
// FRAGMENT order (validated r8-r12):
//   byte addr = (k>>5)*32768 + (i>>6)*4096 + ((i>>4)&3)*1024
//             + (((k>>3)&3)*16 + (i&15))*16
// ---------------------------------------------------------------------------
__global__ __launch_bounds__(64) void k1_prep(
    const float* __restrict__ emb, const float* __restrict__ kern,
    const int* __restrict__ label, unsigned short* __restrict__ wsA,
    float* __restrict__ ws_target, float* __restrict__ ws_ctm,
    float* __restrict__ ws_ft) {
  const int i = blockIdx.x;
  const int l = threadIdx.x;

  const float4* er = reinterpret_cast<const float4*>(emb + (size_t)i * DD + l * 8);
  float4 v0 = er[0], v1 = er[1];
  float e[8] = {v0.x, v0.y, v0.z, v0.w, v1.x, v1.y, v1.z, v1.w};

  float esq = 0.f;
#pragma unroll
  for (int j = 0; j < 8; ++j) esq += e[j] * e[j];
#pragma unroll
  for (int o = 32; o > 0; o >>= 1) esq += __shfl_xor(esq, o);
  const float inv = rsqrtf(esq);

  const int c = label[i];
  float dot = 0.f, wsq = 0.f;
#pragma unroll
  for (int j = 0; j < 8; ++j) {
    float w = kern[(size_t)(l * 8 + j) * CC + c];
    dot += e[j] * w;
    wsq += w * w;
  }
#pragma unroll
  for (int o = 32; o > 0; o >>= 1) {
    dot += __shfl_xor(dot, o);
    wsq += __shfl_xor(wsq, o);
  }

  unsigned int pk[4];
#pragma unroll
  for (int j = 0; j < 4; ++j) {
    unsigned int lo = f2bf(e[2 * j] * inv);
    unsigned int hi = f2bf(e[2 * j + 1] * inv);
    pk[j] = lo | (hi << 16);
  }
  const int off = (l >> 2) * 32768 + (i >> 6) * 4096 + (((i >> 4) & 3)) * 1024 +
                  ((l & 3) * 16 + (i & 15)) * 16;
  uint4 v; v.x = pk[0]; v.y = pk[1]; v.z = pk[2]; v.w = pk[3];
  *reinterpret_cast<uint4*>(reinterpret_cast<char*>(wsA) + off) = v;

  if (l == 0) {
    float t = dot * rsqrtf(fmaxf(esq * wsq, 1e-30f));
    t = fminf(fmaxf(t, -1.f), 1.f);
    float st = sqrtf(fmaxf(0.f, 1.f - t * t));
    float ctm = t * COS_M_C - st * SIN_M_C;
    ws_target[i] = t;
    ws_ctm[i] = ctm;
    ws_ft[i] = (t > THRESH_C) ? ctm : (t - MM_C);
  }
}

// ---------------------------------------------------------------------------
// Kernel 2: deterministic reduction of 512 target logits -> t_new
// ---------------------------------------------------------------------------
__global__ __launch_bounds__(64) void k2_tnew(const float* __restrict__ ws_target,
                                              const float* __restrict__ t_in,
                                              float* __restrict__ ws_tnew) {
  const int l = threadIdx.x;
  float s = 0.f;
#pragma unroll
  for (int j = 0; j < 8; ++j) s += ws_target[l * 8 + j];
#pragma unroll
  for (int o = 32; o > 0; o >>= 1) s += __shfl_xor(s, o);
  if (l == 0) ws_tnew[0] = 0.01f * (s * (1.0f / 512.0f)) + 0.99f * t_in[0];
}

// ---------------------------------------------------------------------------
// Kernel 3: 256x128 tile GEMM + epilogue — DRAM-granule doubling.
//  - Per k-row a wave loads 128 cols = 512 B contiguous (lane = float2).
//  - Out-writes: waves (wv&1)=0/1 cover adjacent 64-col halves of the same
//    rows -> 512 B dirty spans.
//  - Same-XCD mt-pairing: xcd=b&7, j=b>>3, mt=j&1, nt=(j>>1)*8+xcd. Both
//    blocks reading a kern column share one XCD's L2 (fixes r12's 2x FETCH).
//  - A: direct global->VGPR fragment loads from fragment-order wsA.
//  - B: LDS double-buffer 2x8KB [128n][32k] bf16 + chunk swizzle; one
//    barrier/iter; wave wv supplies k-rows wv*4..+3 for its 2 cols/lane.
// Steady-state queue at iter entry: [B(kt+1):4].
//   issue af:4 -> vmcnt(4) retires B regs -> BWRITE -> BLOAD(kt+2):4
//   -> ds_reads -> vmcnt(4) retires af -> lgkm0 -> MFMA -> barrier.
//   Tails (kt>=14): vmcnt(0).
// ---------------------------------------------------------------------------
__global__ __launch_bounds__(512, 4) void k3_gemm(
    const float* __restrict__ kern, const unsigned short* __restrict__ wsA,
    const int* __restrict__ label, const float* __restrict__ ws_ctm,
    const float* __restrict__ ws_ft, const float* __restrict__ ws_tnew,
    float* __restrict__ out) {
  __shared__ __align__(16) char smem[16384 + 8704];  // B 2x8KB + est 8x1088B
  __shared__ float colsq[128];

  const int t = threadIdx.x;
  const int l = t & 63;
  const int wv = t >> 6;  // 0..7;  m-row = wv>>1, n-half = wv&1
  const int lr = l & 15;
  const int lg = l >> 4;

  const int xcd = blockIdx.x & 7;
  const int j = blockIdx.x >> 3;
  const int mt = j & 1;
  const int nt = (j >> 1) * 8 + xcd;
  if (nt >= NT_TILES) return;
  const int n0 = nt * 128;

  if (t < 128) colsq[t] = 0.f;

  // B staging: lane owns cols gc0 = n0+2l, gc0+1 (clamped; junk cols are
  // only ever stored through the c4<CC guard)
  int gc0 = n0 + 2 * l;
  gc0 = gc0 <= (CC - 2) ? gc0 : (CC - 2);
  const float* bcol = kern + gc0;

  float ssqa = 0.f, ssqb = 0.f;

  f32x4 acc[4][4];
#pragma unroll
  for (int a = 0; a < 4; ++a)
#pragma unroll
    for (int b = 0; b < 4; ++b) acc[a][b] = (f32x4){0.f, 0.f, 0.f, 0.f};

  char* Bb = smem;
  const char* pA =
      reinterpret_cast<const char*>(wsA) + (mt * 4 + (wv >> 1)) * 4096 + l * 16;
  // read: k-slice lg of LDS row n -> chunk = lg ^ (n&3) ^ ((n>>2)&3)
  const int nbase = (wv & 1) * 64;
  // write: k-slice (wv>>1), half (wv&1), rows 2l and 2l+1
#define BSWZ(N, S) (((S) ^ ((N)&3) ^ (((N) >> 2) & 3)) << 4)
  const int wb0 = (2 * l) * 64 + BSWZ(2 * l, wv >> 1) + ((wv & 1) << 3);
  const int wb1 = (2 * l + 1) * 64 + BSWZ(2 * l + 1, wv >> 1) + ((wv & 1) << 3);

#define BLOAD(KT, ra, rb, rc, rd)                                        \
  {                                                                      \
    const float* q_ = bcol + (size_t)((KT) * 32 + wv * 4) * CC;          \
    ra = *reinterpret_cast<const float2*>(q_);                           \
    rb = *reinterpret_cast<const float2*>(q_ + (size_t)CC);              \
    rc = *reinterpret_cast<const float2*>(q_ + (size_t)2 * CC);          \
    rd = *reinterpret_cast<const float2*>(q_ + (size_t)3 * CC);          \
  }

#define BWRITE(KT, ra, rb, rc, rd)                                       \
  {                                                                      \
    ssqa += ra.x * ra.x + rb.x * rb.x + rc.x * rc.x + rd.x * rd.x;       \
    ssqb += ra.y * ra.y + rb.y * rb.y + rc.y * rc.y + rd.y * rd.y;       \
    uint2 pka_, pkb_;                                                    \
    pka_.x = (unsigned int)f2bf(ra.x) | ((unsigned int)f2bf(rb.x) << 16);\
    pka_.y = (unsigned int)f2bf(rc.x) | ((unsigned int)f2bf(rd.x) << 16);\
    pkb_.x = (unsigned int)f2bf(ra.y) | ((unsigned int)f2bf(rb.y) << 16);\
    pkb_.y = (unsigned int)f2bf(rc.y) | ((unsigned int)f2bf(rd.y) << 16);\
    *reinterpret_cast<uint2*>(Bb + ((KT)&1) * 8192 + wb0) = pka_;        \
    *reinterpret_cast<uint2*>(Bb + ((KT)&1) * 8192 + wb1) = pkb_;        \
  }

  // ---- prologue ----
  float2 qa, qb, qc, qd;  // B(0)
  float2 pa, pb, pc, pd;  // B(kt+1), loop-carried
  BLOAD(0, qa, qb, qc, qd);
  FENCE();
  BLOAD(1, pa, pb, pc, pd);
  FENCE();
  // queue: [B0:4, B1:4]
  asm volatile("s_waitcnt vmcnt(4)" ::: "memory");  // B0 landed
  BWRITE(0, qa, qb, qc, qd);
  asm volatile("s_waitcnt lgkmcnt(0)" ::: "memory");
  FENCE();
  __builtin_amdgcn_s_barrier();
  FENCE();
  // enter loop: queue = [B1:4]

  for (int kt = 0; kt < 16; ++kt) {
    const int cur = kt & 1;
    // 1. issue A fragment loads (direct from global, L2-hot)
    short8 af[4];
#pragma unroll
    for (int mf = 0; mf < 4; ++mf)
      af[mf] = *reinterpret_cast<const short8*>(pA + kt * 32768 + mf * 1024);
    FENCE();
    // 2-4. retire B(kt+1) regs (iter-old), commit to idle buf, issue B(kt+2)
    if (kt < 15) {
      asm volatile("s_waitcnt vmcnt(4)" ::: "memory");
      BWRITE(kt + 1, pa, pb, pc, pd);
    }
    if (kt < 14) {
      BLOAD(kt + 2, pa, pb, pc, pd);
    }
    FENCE();
    // 5. B fragment ds_reads from current buffer (wave's 64-col half)
    short8 bfr[4];
#pragma unroll
    for (int nf = 0; nf < 4; ++nf) {
      const int n = nbase + nf * 16 + lr;
      bfr[nf] = *reinterpret_cast<const short8*>(Bb + cur * 8192 + n * 64 +
                                                 BSWZ(n, lg));
    }
    // 6. af landed (B(kt+2) stays in flight across the barrier)
    if (kt < 14) {
      asm volatile("s_waitcnt vmcnt(4)" ::: "memory");
    } else {
      asm volatile("s_waitcnt vmcnt(0)" ::: "memory");
    }
    asm volatile("s_waitcnt lgkmcnt(0)" ::: "memory");
    FENCE();
    // 7. MFMA
    __builtin_amdgcn_s_setprio(1);
#pragma unroll
    for (int mf = 0; mf < 4; ++mf)
#pragma unroll
      for (int nf = 0; nf < 4; ++nf)
        acc[mf][nf] = __builtin_amdgcn_mfma_f32_16x16x32_bf16(
            af[mf], bfr[nf], acc[mf][nf], 0, 0, 0);
    __builtin_amdgcn_s_setprio(0);
    FENCE();
    // 8. single barrier
    __builtin_amdgcn_s_barrier();
    FENCE();
  }

  // ---- column-norm reduce (8 waves, disjoint k-rows) ----
  atomicAdd(&colsq[2 * l], ssqa);
  atomicAdd(&colsq[2 * l + 1], ssqb);
  asm volatile("s_waitcnt lgkmcnt(0)" ::: "memory");
  FENCE();
  __builtin_amdgcn_s_barrier();
  FENCE();

  const float tnew = ws_tnew[0];
  float invn[4];
#pragma unroll
  for (int nf = 0; nf < 4; ++nf)
    invn[nf] = rsqrtf(fmaxf(colsq[nbase + nf * 16 + lr], 1e-30f));

  // ---- epilogue: 4-row phased transpose through wave-private LDS ----
  float* est = reinterpret_cast<float*>(smem + 16384) + (size_t)wv * 272;
  const int c4 = n0 + nbase + lr * 4;
#pragma unroll
  for (int mf = 0; mf < 4; ++mf) {
#pragma unroll
    for (int p = 0; p < 4; ++p) {
      asm volatile("s_waitcnt lgkmcnt(0)" ::: "memory");  // WAR vs prev phase
      FENCE();
      if (lg == p) {
#pragma unroll
        for (int r = 0; r < 4; ++r)
#pragma unroll
          for (int nf = 0; nf < 4; ++nf)
            est[r * 68 + nf * 16 + lr] = acc[mf][nf][r] * invn[nf];
      }
      asm volatile("s_waitcnt lgkmcnt(0)" ::: "memory");  // RAW
      FENCE();
      const int m = mt * 256 + (wv >> 1) * 64 + mf * 16 + p * 4 + lg;
      const float ctm = ws_ctm[m];
      const float ft = ws_ft[m];
      const int lab = label[m];
      float4 vv = *reinterpret_cast<const float4*>(&est[lg * 68 + lr * 4]);
      if (c4 < CC) {
        float ov[4] = {vv.x, vv.y, vv.z, vv.w};
#pragma unroll
        for (int jj = 0; jj < 4; ++jj) {
          float cosv = fminf(fmaxf(ov[jj], -1.f), 1.f);
          float val = (cosv > ctm) ? cosv * (tnew + cosv) : cosv;
          if (c4 + jj == lab) val = ft;
          ov[jj] = val * S_SCALE;
        }
        float4 st4;
        st4.x = ov[0]; st4.y = ov[1]; st4.z = ov[2]; st4.w = ov[3];
        *reinterpret_cast<float4*>(out + (size_t)m * CC + c4) = st4;
      }
    }
  }
#undef BLOAD
#undef BWRITE
#undef BSWZ
}

// ---------------------------------------------------------------------------
extern "C" void kernel_launch(void* const* d_in, const int* in_sizes, int n_in,
                              void* d_out, int out_size, void* d_ws,
                              size_t ws_size, hipStream_t stream) {
  (void)in_sizes; (void)n_in; (void)out_size; (void)ws_size;
  const float* emb = (const float*)d_in[0];
  const float* kern = (const float*)d_in[1];
  const int* label = (const int*)d_in[2];
  const float* t_in = (const float*)d_in[3];
  float* out = (float*)d_out;

  char* ws = (char*)d_ws;
  unsigned short* wsA = (unsigned short*)ws;
  float* ws_target = (float*)(ws + 524288);
  float* ws_ctm = (float*)(ws + 526336);
  float* ws_ft = (float*)(ws + 528384);
  float* ws_tnew = (float*)(ws + 530432);

  k1_prep<<<512, 64, 0, stream>>>(emb, kern, label, wsA, ws_target, ws_ctm, ws_ft);
  k2_tnew<<<1, 64, 0, stream>>>(ws_target, t_in, ws_tnew);
  // grid: ceil(782 nt / 8 xcd)=98 hi-groups x 2 mt x 8 xcd = 1568 blocks
  k3_gemm<<<98 * 16, 512, 0, stream>>>(kern, wsA, label, ws_ctm, ws_ft,
                                       ws_tnew, out);
}